// Round 2
// baseline (870.755 us; speedup 1.0000x reference)
//
#include <hip/hip_runtime.h>
#include <math.h>

typedef __bf16 bf16;
typedef __bf16 bf16x8 __attribute__((ext_vector_type(8)));
typedef float f32x4 __attribute__((ext_vector_type(4)));

#define HEADS 16
#define NOPE 128
#define VDIM 128
#define ROPE 64
#define QHEAD 192
#define KVRANK 512
#define NB 2
#define SEQ 2048
#define ROWS (NB * SEQ)

// ---------------------------------------------------------------------------
// fp32 -> bf16 elementwise convert (for x)
// ---------------------------------------------------------------------------
__global__ __launch_bounds__(256) void convert_f32_bf16(
    const float* __restrict__ in, bf16* __restrict__ out, size_t n)
{
    size_t i = ((size_t)blockIdx.x * 256 + threadIdx.x) * 4;
    if (i + 3 < n) {
        float4 v = *(const float4*)(in + i);
        out[i]     = (bf16)v.x;
        out[i + 1] = (bf16)v.y;
        out[i + 2] = (bf16)v.z;
        out[i + 3] = (bf16)v.w;
    } else {
        for (size_t j = i; j < n; j++) out[j] = (bf16)in[j];
    }
}

// ---------------------------------------------------------------------------
// Transpose + convert: out_bf16[C,R] = in_f32[R,C]
// ---------------------------------------------------------------------------
__global__ __launch_bounds__(256) void transpose_f32_bf16(
    const float* __restrict__ in, bf16* __restrict__ out, int R, int Ccols)
{
    __shared__ float tile[32][33];
    int bx = blockIdx.x * 32, by = blockIdx.y * 32;
    int tx = threadIdx.x & 31, ty = threadIdx.x >> 5;   // 32 x 8
    for (int i = 0; i < 32; i += 8) {
        int r = by + ty + i, c = bx + tx;
        tile[ty + i][tx] = (r < R && c < Ccols) ? in[(size_t)r * Ccols + c] : 0.f;
    }
    __syncthreads();
    for (int i = 0; i < 32; i += 8) {
        int c = bx + ty + i, r = by + tx;
        if (c < Ccols && r < R) out[(size_t)c * R + r] = (bf16)tile[tx][ty + i];
    }
}

// ---------------------------------------------------------------------------
// Generic bf16 GEMM: C[M,N] = A[M,K] @ Bt[N,K]^T   (Bt is B transposed)
// 128x128 tile, 4 waves, 4x4 MFMA tiles (16x16x32) per wave.
// OutT = bf16 (intermediates) or float (final output).
// ---------------------------------------------------------------------------
template <typename OutT>
__global__ __launch_bounds__(256) void gemm_bf16(
    const bf16* __restrict__ A, int lda,
    const bf16* __restrict__ Bt, int ldb,
    OutT* __restrict__ C, int ldc,
    int M, int N, int K)
{
    __shared__ bf16 As[128][40];
    __shared__ bf16 Bs[128][40];
    const int tid  = threadIdx.x;
    const int wave = tid >> 6, lane = tid & 63;
    const int quad = lane >> 4, l16 = lane & 15;
    const int bm = blockIdx.x * 128, bn = blockIdx.y * 128;
    const int wm = (wave >> 1) * 64, wn = (wave & 1) * 64;

    f32x4 acc[4][4];
    for (int i = 0; i < 4; i++)
        for (int j = 0; j < 4; j++)
            acc[i][j] = (f32x4){0.f, 0.f, 0.f, 0.f};

    for (int k0 = 0; k0 < K; k0 += 32) {
        for (int i = 0; i < 2; i++) {
            int chunk = tid + i * 256;        // 0..511
            int r = chunk >> 2;               // 0..127
            int c = (chunk & 3) << 3;         // 0,8,16,24
            uint4 va = make_uint4(0u, 0u, 0u, 0u);
            int gr = bm + r;
            if (gr < M) va = *(const uint4*)(A + (size_t)gr * lda + k0 + c);
            *(uint4*)&As[r][c] = va;
            uint4 vb = make_uint4(0u, 0u, 0u, 0u);
            int gn = bn + r;
            if (gn < N) vb = *(const uint4*)(Bt + (size_t)gn * ldb + k0 + c);
            *(uint4*)&Bs[r][c] = vb;
        }
        __syncthreads();
        bf16x8 af[4], bfv[4];
        for (int mi = 0; mi < 4; mi++)
            af[mi] = *(const bf16x8*)&As[wm + mi * 16 + l16][quad * 8];
        for (int ni = 0; ni < 4; ni++)
            bfv[ni] = *(const bf16x8*)&Bs[wn + ni * 16 + l16][quad * 8];
        for (int mi = 0; mi < 4; mi++)
            for (int ni = 0; ni < 4; ni++)
                acc[mi][ni] = __builtin_amdgcn_mfma_f32_16x16x32_bf16(
                    af[mi], bfv[ni], acc[mi][ni], 0, 0, 0);
        __syncthreads();
    }

    for (int mi = 0; mi < 4; mi++)
        for (int ni = 0; ni < 4; ni++) {
            int col = bn + wn + ni * 16 + l16;
            if (col >= N) continue;
            int row0 = bm + wm + mi * 16 + quad * 4;
            for (int r = 0; r < 4; r++) {
                int row = row0 + r;
                if (row < M) C[(size_t)row * ldc + col] = (OutT)acc[mi][ni][r];
            }
        }
}

// ---------------------------------------------------------------------------
// prep_q: q[ROWS,3072] -> qf[b,h,n,192] with RoPE on last 64 dims
// ---------------------------------------------------------------------------
__global__ __launch_bounds__(256) void prep_q(
    const bf16* __restrict__ q, bf16* __restrict__ qf)
{
    int row = blockIdx.x;                 // 0..4095
    int b = row >> 11, n = row & 2047;
    int tid = threadIdx.x;
    for (int h = 0; h < HEADS; h++) {
        size_t src = (size_t)row * (HEADS * QHEAD) + h * QHEAD;
        size_t dst = ((size_t)(b * HEADS + h) * SEQ + n) * QHEAD;
        if (tid < 128) {
            qf[dst + tid] = q[src + tid];
        } else if (tid < 160) {
            int i = tid - 128;            // pair index 0..31
            float x1 = (float)q[src + 128 + 2 * i];
            float x2 = (float)q[src + 128 + 2 * i + 1];
            float theta = powf(10000.f, -(float)i / 32.f);
            float sn, cs;
            sincosf((float)n * theta, &sn, &cs);
            qf[dst + 128 + 2 * i]     = (bf16)(x1 * cs - x2 * sn);
            qf[dst + 128 + 2 * i + 1] = (bf16)(x1 * sn + x2 * cs);
        }
    }
}

// ---------------------------------------------------------------------------
// prep_kv: build kf[b,h,n,192] from kv[ROWS,4096] (k_nope) + ckv[ROWS,576]
// (roped k_pe, broadcast over heads)
// ---------------------------------------------------------------------------
__global__ __launch_bounds__(256) void prep_kv(
    const bf16* __restrict__ ckv, const bf16* __restrict__ kv,
    bf16* __restrict__ kf)
{
    int row = blockIdx.x;
    int b = row >> 11, n = row & 2047;
    int tid = threadIdx.x;
    __shared__ float kro[64];
    if (tid < 32) {
        int i = tid;
        float x1 = (float)ckv[(size_t)row * 576 + 512 + 2 * i];
        float x2 = (float)ckv[(size_t)row * 576 + 512 + 2 * i + 1];
        float theta = powf(10000.f, -(float)i / 32.f);
        float sn, cs;
        sincosf((float)n * theta, &sn, &cs);
        kro[2 * i]     = x1 * cs - x2 * sn;
        kro[2 * i + 1] = x1 * sn + x2 * cs;
    }
    __syncthreads();
    for (int h = 0; h < HEADS; h++) {
        size_t dst = ((size_t)(b * HEADS + h) * SEQ + n) * QHEAD;
        if (tid < 128) {
            kf[dst + tid] = kv[(size_t)row * (HEADS * 256) + h * 256 + tid];
        } else if (tid < 192) {
            kf[dst + tid] = (bf16)kro[tid - 128];
        }
    }
}

// ---------------------------------------------------------------------------
// Flash attention (causal). Block = (qtile of 64 rows, h, b); 4 waves, each
// wave owns a 16-row Q strip. K-tile = 64.
// ---------------------------------------------------------------------------
__global__ __launch_bounds__(256) void attn_fa(
    const bf16* __restrict__ qf, const bf16* __restrict__ kf,
    const bf16* __restrict__ kv, bf16* __restrict__ attn_out)
{
    __shared__ bf16 Ks[64][200];     // [kpos][d] d=0..191, pad->200
    __shared__ bf16 Vt[128][72];     // [dv][kpos], pad->72
    __shared__ bf16 Ps[4][16][72];   // per-wave P, [q][kpos]

    const int qt = blockIdx.x;       // 0..31
    const int h  = blockIdx.y;       // 0..15
    const int b  = blockIdx.z;       // 0..1
    const int tid  = threadIdx.x;
    const int wave = tid >> 6, lane = tid & 63;
    const int quad = lane >> 4, l16 = lane & 15;
    const float scale = 0.072168783648703332f;   // 1/sqrt(192)

    const size_t bh = (size_t)(b * HEADS + h);

    // Q fragments for this wave's 16-row strip (held in registers)
    bf16x8 aq[6];
    {
        const bf16* qbase = qf + (bh * SEQ + qt * 64 + wave * 16 + l16) * QHEAD;
        for (int ks = 0; ks < 6; ks++)
            aq[ks] = *(const bf16x8*)(qbase + ks * 32 + quad * 8);
    }

    f32x4 o[8];
    for (int i = 0; i < 8; i++) o[i] = (f32x4){0.f, 0.f, 0.f, 0.f};
    float m_i[4] = {-1e30f, -1e30f, -1e30f, -1e30f};
    float l_i[4] = {0.f, 0.f, 0.f, 0.f};

    const int ntiles = qt + 1;
    for (int kt = 0; kt < ntiles; kt++) {
        // stage K tile: 64 x 192
        for (int i = 0; i < 6; i++) {
            int c = tid + i * 256;           // 0..1535
            int r = c / 24;
            int col = (c % 24) * 8;
            *(uint4*)&Ks[r][col] =
                *(const uint4*)(kf + (bh * SEQ + kt * 64 + r) * QHEAD + col);
        }
        // stage V tile transposed: Vt[dv][kpos]
        for (int i = 0; i < 4; i++) {
            int c = tid + i * 256;           // 0..1023
            int r = c >> 4;                  // kpos 0..63
            int dv0 = (c & 15) << 3;
            uint4 v4 = *(const uint4*)(kv + ((size_t)(b * SEQ + kt * 64 + r)) * (HEADS * 256)
                                       + h * 256 + 128 + dv0);
            const bf16* pv = (const bf16*)&v4;
            for (int j = 0; j < 8; j++) Vt[dv0 + j][r] = pv[j];
        }
        __syncthreads();

        // S = Q K^T  (16 x 64 per wave)
        f32x4 sacc[4];
        for (int nt = 0; nt < 4; nt++) sacc[nt] = (f32x4){0.f, 0.f, 0.f, 0.f};
        for (int ks = 0; ks < 6; ks++)
            for (int nt = 0; nt < 4; nt++) {
                bf16x8 bk = *(const bf16x8*)&Ks[nt * 16 + l16][ks * 32 + quad * 8];
                sacc[nt] = __builtin_amdgcn_mfma_f32_16x16x32_bf16(aq[ks], bk, sacc[nt], 0, 0, 0);
            }

        // online softmax
        int qbase_row = qt * 64 + wave * 16 + quad * 4;
        float ptile[4][4];
        for (int r = 0; r < 4; r++) {
            float mx = m_i[r];
            for (int nt = 0; nt < 4; nt++) {
                int kpos = kt * 64 + nt * 16 + l16;
                float s = sacc[nt][r] * scale;
                if (kpos > qbase_row + r) s = -1e30f;
                ptile[nt][r] = s;
                mx = fmaxf(mx, s);
            }
            for (int off = 8; off; off >>= 1) mx = fmaxf(mx, __shfl_xor(mx, off));
            float alpha = __expf(m_i[r] - mx);
            float rs = 0.f;
            for (int nt = 0; nt < 4; nt++) {
                float p = __expf(ptile[nt][r] - mx);
                ptile[nt][r] = p;
                rs += p;
            }
            for (int off = 8; off; off >>= 1) rs += __shfl_xor(rs, off);
            l_i[r] = l_i[r] * alpha + rs;
            m_i[r] = mx;
            for (int nv = 0; nv < 8; nv++) o[nv][r] *= alpha;
        }

        // P -> LDS (C-layout -> A-layout round trip)
        for (int nt = 0; nt < 4; nt++)
            for (int r = 0; r < 4; r++)
                Ps[wave][quad * 4 + r][nt * 16 + l16] = (bf16)ptile[nt][r];
        __syncthreads();

        // O += P V
        for (int ks2 = 0; ks2 < 2; ks2++) {
            bf16x8 ap = *(const bf16x8*)&Ps[wave][l16][ks2 * 32 + quad * 8];
            for (int nv = 0; nv < 8; nv++) {
                bf16x8 bv = *(const bf16x8*)&Vt[nv * 16 + l16][ks2 * 32 + quad * 8];
                o[nv] = __builtin_amdgcn_mfma_f32_16x16x32_bf16(ap, bv, o[nv], 0, 0, 0);
            }
        }
        __syncthreads();
    }

    // epilogue: attn_out[b*SEQ+n][h*128+dv]
    for (int r = 0; r < 4; r++) {
        float inv = 1.f / l_i[r];
        int row = b * SEQ + qt * 64 + wave * 16 + quad * 4 + r;
        for (int nv = 0; nv < 8; nv++)
            attn_out[(size_t)row * (HEADS * VDIM) + h * VDIM + nv * 16 + l16] =
                (bf16)(o[nv][r] * inv);
    }
}

// ---------------------------------------------------------------------------
extern "C" void kernel_launch(void* const* d_in, const int* in_sizes, int n_in,
                              void* d_out, int out_size, void* d_ws, size_t ws_size,
                              hipStream_t stream)
{
    const float* x    = (const float*)d_in[0];
    const float* Wqa  = (const float*)d_in[1];
    const float* Wqb  = (const float*)d_in[2];
    const float* Wkva = (const float*)d_in[3];
    const float* Wkvb = (const float*)d_in[4];
    const float* Wout = (const float*)d_in[5];
    float* out = (float*)d_out;

    char* ws = (char*)d_ws;
    size_t off = 0;
    auto alloc = [&](size_t elems) { char* p = ws + off; off += elems * sizeof(bf16); return (bf16*)p; };
    bf16* xb    = alloc((size_t)ROWS * 2048);
    bf16* WqaT  = alloc((size_t)512 * 2048);
    bf16* WqbT  = alloc((size_t)3072 * 512);
    bf16* WkvaT = alloc((size_t)576 * 2048);
    bf16* WkvbT = alloc((size_t)4096 * 512);
    bf16* WoutT = alloc((size_t)2048 * 2048);
    bf16* t1    = alloc((size_t)ROWS * 512);
    bf16* q     = alloc((size_t)ROWS * 3072);
    bf16* ckv   = alloc((size_t)ROWS * 576);
    bf16* kv    = alloc((size_t)ROWS * 4096);
    bf16* qf    = alloc((size_t)NB * HEADS * SEQ * QHEAD);
    bf16* kf    = alloc((size_t)NB * HEADS * SEQ * QHEAD);
    bf16* attn  = alloc((size_t)ROWS * 2048);
    if (off > ws_size) return;   // workspace too small — distinguishable failure (absmax = max|ref|)

    dim3 blk(256);

    // input conversion
    convert_f32_bf16<<<dim3((ROWS * 2048 / 4 + 255) / 256), blk, 0, stream>>>(x, xb, (size_t)ROWS * 2048);

    // weight transposes (fp32 -> bf16)
    transpose_f32_bf16<<<dim3(512 / 32, 2048 / 32), blk, 0, stream>>>(Wqa, WqaT, 2048, 512);
    transpose_f32_bf16<<<dim3(3072 / 32, 512 / 32), blk, 0, stream>>>(Wqb, WqbT, 512, 3072);
    transpose_f32_bf16<<<dim3(576 / 32, 2048 / 32), blk, 0, stream>>>(Wkva, WkvaT, 2048, 576);
    transpose_f32_bf16<<<dim3(4096 / 32, 512 / 32), blk, 0, stream>>>(Wkvb, WkvbT, 512, 4096);
    transpose_f32_bf16<<<dim3(2048 / 32, 2048 / 32), blk, 0, stream>>>(Wout, WoutT, 2048, 2048);

    // GEMM1: t1 = x @ Wqa        [4096,512]  K=2048
    gemm_bf16<bf16><<<dim3(32, 4), blk, 0, stream>>>(xb, 2048, WqaT, 2048, t1, 512, ROWS, 512, 2048);
    // GEMM3: ckv = x @ Wkva      [4096,576]  K=2048
    gemm_bf16<bf16><<<dim3(32, 5), blk, 0, stream>>>(xb, 2048, WkvaT, 2048, ckv, 576, ROWS, 576, 2048);
    // GEMM2: q = t1 @ Wqb        [4096,3072] K=512
    gemm_bf16<bf16><<<dim3(32, 24), blk, 0, stream>>>(t1, 512, WqbT, 512, q, 3072, ROWS, 3072, 512);
    // GEMM4: kv = ckv[:, :512] @ Wkvb  [4096,4096] K=512
    gemm_bf16<bf16><<<dim3(32, 32), blk, 0, stream>>>(ckv, 576, WkvbT, 512, kv, 4096, ROWS, 4096, 512);

    // RoPE / packing
    prep_q<<<dim3(ROWS), blk, 0, stream>>>(q, qf);
    prep_kv<<<dim3(ROWS), blk, 0, stream>>>(ckv, kv, kf);

    // flash attention
    attn_fa<<<dim3(SEQ / 64, HEADS, NB), blk, 0, stream>>>(qf, kf, kv, attn);

    // GEMM5: out = attn @ Wout   [4096,2048] K=2048  (fp32 output)
    gemm_bf16<float><<<dim3(32, 16), blk, 0, stream>>>(attn, 2048, WoutT, 2048, out, 2048, ROWS, 2048, 2048);
}

// Round 3
// 498.772 us; speedup vs baseline: 1.7458x; 1.7458x over previous
//
#include <hip/hip_runtime.h>
#include <math.h>

typedef __bf16 bf16;
typedef __bf16 bf16x8 __attribute__((ext_vector_type(8)));
typedef float f32x4 __attribute__((ext_vector_type(4)));

#define HEADS 16
#define QHEAD 192
#define NB 2
#define SEQ 2048
#define ROWS (NB * SEQ)
#define QSCALE 0.07216878364870322f   /* 1/sqrt(192), folded into q */

// ---------------------------------------------------------------------------
// fp32 -> bf16 elementwise convert (for x)
// ---------------------------------------------------------------------------
__global__ __launch_bounds__(256) void convert_f32_bf16(
    const float* __restrict__ in, bf16* __restrict__ out, size_t n)
{
    size_t i = ((size_t)blockIdx.x * 256 + threadIdx.x) * 4;
    if (i + 3 < n) {
        float4 v = *(const float4*)(in + i);
        out[i]     = (bf16)v.x;
        out[i + 1] = (bf16)v.y;
        out[i + 2] = (bf16)v.z;
        out[i + 3] = (bf16)v.w;
    } else {
        for (size_t j = i; j < n; j++) out[j] = (bf16)in[j];
    }
}

// ---------------------------------------------------------------------------
// Transpose + convert: out_bf16[C,R] = in_f32[R,C]
// ---------------------------------------------------------------------------
__global__ __launch_bounds__(256) void transpose_f32_bf16(
    const float* __restrict__ in, bf16* __restrict__ out, int R, int Ccols)
{
    __shared__ float tile[32][33];
    int bx = blockIdx.x * 32, by = blockIdx.y * 32;
    int tx = threadIdx.x & 31, ty = threadIdx.x >> 5;   // 32 x 8
    for (int i = 0; i < 32; i += 8) {
        int r = by + ty + i, c = bx + tx;
        tile[ty + i][tx] = (r < R && c < Ccols) ? in[(size_t)r * Ccols + c] : 0.f;
    }
    __syncthreads();
    for (int i = 0; i < 32; i += 8) {
        int c = bx + ty + i, r = by + tx;
        if (c < Ccols && r < R) out[(size_t)c * R + r] = (bf16)tile[tx][ty + i];
    }
}

// ---------------------------------------------------------------------------
// bf16 GEMM, m97 recipe: C[M,N] = A[M,K] @ Bt[N,K]^T
// 128x128 tile, BK=32, packed LDS, global_load_lds width-16 staging.
// Staging has NO bounds guards: M and padded Bt rows must be >= tile coverage.
// ---------------------------------------------------------------------------
template <typename OutT>
__global__ __launch_bounds__(256) void gemm_bf16(
    const bf16* __restrict__ A, int lda,
    const bf16* __restrict__ Bt, int ldb,
    OutT* __restrict__ C, int ldc,
    int M, int N, int K)
{
    __shared__ bf16 As[128 * 32];
    __shared__ bf16 Bs[128 * 32];
    const int tid  = threadIdx.x;
    const int wave = tid >> 6, lane = tid & 63;
    const int quad = lane >> 4, l16 = lane & 15;
    const int bm = blockIdx.x * 128, bn = blockIdx.y * 128;
    const int wm = (wave >> 1) * 64, wn = (wave & 1) * 64;
    const int srow = lane >> 2, scol = (lane & 3) * 8;   // 4 lanes per 32-elem row

    f32x4 acc[4][4];
    for (int i = 0; i < 4; i++)
        for (int j = 0; j < 4; j++)
            acc[i][j] = (f32x4){0.f, 0.f, 0.f, 0.f};

    for (int k0 = 0; k0 < K; k0 += 32) {
#pragma unroll
        for (int s2 = 0; s2 < 2; s2++) {
            const int seg = wave * 2 + s2;              // 0..7, 16 rows each
            const bf16* ga = A  + (size_t)(bm + seg * 16 + srow) * lda + k0 + scol;
            const bf16* gb = Bt + (size_t)(bn + seg * 16 + srow) * ldb + k0 + scol;
            __builtin_amdgcn_global_load_lds(
                (const __attribute__((address_space(1))) void*)ga,
                (__attribute__((address_space(3))) void*)&As[seg * 512], 16, 0, 0);
            __builtin_amdgcn_global_load_lds(
                (const __attribute__((address_space(1))) void*)gb,
                (__attribute__((address_space(3))) void*)&Bs[seg * 512], 16, 0, 0);
        }
        __syncthreads();
        bf16x8 af[4], bfv[4];
        for (int mi = 0; mi < 4; mi++)
            af[mi] = *(const bf16x8*)&As[(wm + mi * 16 + l16) * 32 + quad * 8];
        for (int ni = 0; ni < 4; ni++)
            bfv[ni] = *(const bf16x8*)&Bs[(wn + ni * 16 + l16) * 32 + quad * 8];
        for (int mi = 0; mi < 4; mi++)
            for (int ni = 0; ni < 4; ni++)
                acc[mi][ni] = __builtin_amdgcn_mfma_f32_16x16x32_bf16(
                    af[mi], bfv[ni], acc[mi][ni], 0, 0, 0);
        __syncthreads();
    }

    for (int mi = 0; mi < 4; mi++)
        for (int ni = 0; ni < 4; ni++) {
            int col = bn + wn + ni * 16 + l16;
            if (col >= N) continue;
            int row0 = bm + wm + mi * 16 + quad * 4;
            for (int r = 0; r < 4; r++)
                C[(size_t)(row0 + r) * ldc + col] = (OutT)acc[mi][ni][r];
        }
}

// ---------------------------------------------------------------------------
// prep_q: q[ROWS,3072] -> qf[bh,n,192], RoPE on last 64 dims, *QSCALE folded.
// One uint4 chunk per thread.
// ---------------------------------------------------------------------------
__global__ __launch_bounds__(256) void prep_q(
    const bf16* __restrict__ q, bf16* __restrict__ qf)
{
    int gid = blockIdx.x * 256 + threadIdx.x;   // 0 .. ROWS*384-1
    int row = gid / 384;
    int c   = gid - row * 384;
    int h   = c / 24;
    int off = (c - h * 24) * 8;
    int b = row >> 11, n = row & 2047;
    const bf16* src = q + (size_t)row * 3072 + h * QHEAD + off;
    bf16* dst = qf + (((size_t)(b * HEADS + h)) * SEQ + n) * QHEAD + off;
    uint4 v = *(const uint4*)src;
    const bf16* e = (const bf16*)&v;
    bf16 outv[8];
    if (off < 128) {
        for (int k = 0; k < 8; k++) outv[k] = (bf16)((float)e[k] * QSCALE);
    } else {
        int p0 = (off - 128) >> 1;
        for (int k = 0; k < 4; k++) {
            float x1 = (float)e[2 * k], x2 = (float)e[2 * k + 1];
            float theta = powf(10000.f, -(float)(p0 + k) / 32.f);
            float sn, cs;
            sincosf((float)n * theta, &sn, &cs);
            outv[2 * k]     = (bf16)((x1 * cs - x2 * sn) * QSCALE);
            outv[2 * k + 1] = (bf16)((x1 * sn + x2 * cs) * QSCALE);
        }
    }
    *(uint4*)dst = *(const uint4*)outv;
}

// ---------------------------------------------------------------------------
// prep_kv: kf[bh,n,192] = [k_nope from kv | roped k_pe from ckv (bcast heads)]
// ---------------------------------------------------------------------------
__global__ __launch_bounds__(256) void prep_kv(
    const bf16* __restrict__ ckv, const bf16* __restrict__ kv,
    bf16* __restrict__ kf)
{
    int row = blockIdx.x;
    int b = row >> 11, n = row & 2047;
    int tid = threadIdx.x;
    __shared__ bf16 kro[64];
    if (tid < 32) {
        float x1 = (float)ckv[(size_t)row * 576 + 512 + 2 * tid];
        float x2 = (float)ckv[(size_t)row * 576 + 512 + 2 * tid + 1];
        float theta = powf(10000.f, -(float)tid / 32.f);
        float sn, cs;
        sincosf((float)n * theta, &sn, &cs);
        kro[2 * tid]     = (bf16)(x1 * cs - x2 * sn);
        kro[2 * tid + 1] = (bf16)(x1 * sn + x2 * cs);
    }
    __syncthreads();
    for (int c = tid; c < 384; c += 256) {
        int h = c / 24;
        int off = (c - h * 24) * 8;
        bf16* dst = kf + (((size_t)(b * HEADS + h)) * SEQ + n) * QHEAD + off;
        if (off < 128)
            *(uint4*)dst = *(const uint4*)(kv + (size_t)row * 4096 + h * 256 + off);
        else
            *(uint4*)dst = *(const uint4*)&kro[off - 128];
    }
}

// ---------------------------------------------------------------------------
// vT[bh,dv,n] = kv[b*SEQ+n, h*256+128+dv]  (V transposed once, in global)
// ---------------------------------------------------------------------------
__global__ __launch_bounds__(256) void vt_kernel(
    const bf16* __restrict__ kv, bf16* __restrict__ vT)
{
    __shared__ bf16 tile[32][33];
    int nt0 = blockIdx.x * 32;
    int dv0 = blockIdx.y * 32;
    int bh  = blockIdx.z;
    int b = bh >> 4, h = bh & 15;
    int tx = threadIdx.x & 31, ty = threadIdx.x >> 5;
    for (int i = 0; i < 32; i += 8) {
        int n = nt0 + ty + i;
        tile[ty + i][tx] = kv[((size_t)(b * SEQ + n)) * 4096 + h * 256 + 128 + dv0 + tx];
    }
    __syncthreads();
    for (int i = 0; i < 32; i += 8) {
        int dv = dv0 + ty + i;
        vT[((size_t)bh * 128 + dv) * SEQ + nt0 + tx] = tile[tx][ty + i];
    }
}

// ---------------------------------------------------------------------------
// Flash attention, causal. 512 blocks; block bid handles (bh = bid>>4) and
// q-tiles {pk, 31-pk} (pk = bid&15) -> every block does exactly 33 K-tile
// iterations (perfect load balance; whole grid co-resident at 2 blocks/CU).
// ---------------------------------------------------------------------------
__global__ __launch_bounds__(256) void attn_fa(
    const bf16* __restrict__ qf, const bf16* __restrict__ kf,
    const bf16* __restrict__ vT, bf16* __restrict__ attn_out)
{
    __shared__ bf16 Ks[64][200];     // [kpos][d], 400B rows (16B-aligned, bank-safe)
    __shared__ bf16 Vt[128][72];     // [dv][kpos], 144B rows
    __shared__ bf16 Ps[4][16][72];   // per-wave P (wave-private!)

    const int bid = blockIdx.x;
    const int bh = bid >> 4;         // 0..31
    const int pk = bid & 15;
    const int b = bh >> 4, h = bh & 15;
    const int tid  = threadIdx.x;
    const int wave = tid >> 6, lane = tid & 63;
    const int quad = lane >> 4, l16 = lane & 15;

    for (int pass = 0; pass < 2; pass++) {
        const int qt = pass ? (31 - pk) : pk;

        bf16x8 aq[6];
        {
            const bf16* qbase = qf + ((size_t)bh * SEQ + qt * 64 + wave * 16 + l16) * QHEAD;
            for (int ks = 0; ks < 6; ks++)
                aq[ks] = *(const bf16x8*)(qbase + ks * 32 + quad * 8);
        }
        f32x4 o[8];
        for (int i = 0; i < 8; i++) o[i] = (f32x4){0.f, 0.f, 0.f, 0.f};
        float m_i[4] = {-1e30f, -1e30f, -1e30f, -1e30f};
        float l_i[4] = {0.f, 0.f, 0.f, 0.f};

        for (int kt = 0; kt <= qt; kt++) {
            // stage K tile (64 x 192), vectorized
#pragma unroll
            for (int i = 0; i < 6; i++) {
                int c = tid + i * 256;
                int r = c / 24, col = (c - r * 24) * 8;
                *(uint4*)&Ks[r][col] =
                    *(const uint4*)(kf + ((size_t)bh * SEQ + kt * 64 + r) * QHEAD + col);
            }
            // stage Vt tile (128 dv x 64 kpos) from pre-transposed vT, vectorized
#pragma unroll
            for (int i = 0; i < 4; i++) {
                int c = tid + i * 256;
                int dv = c >> 3, g = c & 7;
                *(uint4*)&Vt[dv][g * 8] =
                    *(const uint4*)(vT + ((size_t)bh * 128 + dv) * SEQ + kt * 64 + g * 8);
            }
            __syncthreads();

            // S = Q K^T  (16 x 64 per wave); q pre-scaled by 1/sqrt(192)
            f32x4 sacc[4];
            for (int nt = 0; nt < 4; nt++) sacc[nt] = (f32x4){0.f, 0.f, 0.f, 0.f};
            for (int ks = 0; ks < 6; ks++)
                for (int nt = 0; nt < 4; nt++) {
                    bf16x8 bk = *(const bf16x8*)&Ks[nt * 16 + l16][ks * 32 + quad * 8];
                    sacc[nt] = __builtin_amdgcn_mfma_f32_16x16x32_bf16(aq[ks], bk, sacc[nt], 0, 0, 0);
                }

            // online softmax; causal mask only on the diagonal tile
            const bool diag = (kt == qt);
            float ptile[4][4];
            for (int r = 0; r < 4; r++) {
                float mx = m_i[r];
                if (diag) {
                    int qrow = wave * 16 + quad * 4 + r;
                    for (int nt = 0; nt < 4; nt++) {
                        int kp = nt * 16 + l16;
                        float s = (kp > qrow) ? -1e30f : sacc[nt][r];
                        ptile[nt][r] = s;
                        mx = fmaxf(mx, s);
                    }
                } else {
                    for (int nt = 0; nt < 4; nt++) {
                        float s = sacc[nt][r];
                        ptile[nt][r] = s;
                        mx = fmaxf(mx, s);
                    }
                }
                mx = fmaxf(mx, __shfl_xor(mx, 8));
                mx = fmaxf(mx, __shfl_xor(mx, 4));
                mx = fmaxf(mx, __shfl_xor(mx, 2));
                mx = fmaxf(mx, __shfl_xor(mx, 1));
                float alpha = __expf(m_i[r] - mx);
                float rs = 0.f;
                for (int nt = 0; nt < 4; nt++) {
                    float p = __expf(ptile[nt][r] - mx);
                    ptile[nt][r] = p;
                    rs += p;
                }
                rs += __shfl_xor(rs, 8);
                rs += __shfl_xor(rs, 4);
                rs += __shfl_xor(rs, 2);
                rs += __shfl_xor(rs, 1);
                l_i[r] = l_i[r] * alpha + rs;
                m_i[r] = mx;
                for (int nv = 0; nv < 8; nv++) o[nv][r] *= alpha;
            }

            // P: C-layout -> A-layout via wave-private LDS (no block barrier:
            // Ps[wave] is only touched by wave `wave`; per-wave DS ops are
            // processed in order. sched_barrier pins compiler ordering.)
            for (int nt = 0; nt < 4; nt++)
                for (int r = 0; r < 4; r++)
                    Ps[wave][quad * 4 + r][nt * 16 + l16] = (bf16)ptile[nt][r];
            __builtin_amdgcn_sched_barrier(0);

            // O += P V
            for (int ks2 = 0; ks2 < 2; ks2++) {
                bf16x8 ap = *(const bf16x8*)&Ps[wave][l16][ks2 * 32 + quad * 8];
                for (int nv = 0; nv < 8; nv++) {
                    bf16x8 bv = *(const bf16x8*)&Vt[nv * 16 + l16][ks2 * 32 + quad * 8];
                    o[nv] = __builtin_amdgcn_mfma_f32_16x16x32_bf16(ap, bv, o[nv], 0, 0, 0);
                }
            }
            __syncthreads();   // protect Ks/Vt before next iteration's staging
        }

        // epilogue: attn_out[b*SEQ+n][h*128+dv]
        for (int r = 0; r < 4; r++) {
            float inv = 1.f / l_i[r];
            size_t row = (size_t)b * SEQ + qt * 64 + wave * 16 + quad * 4 + r;
            for (int nv = 0; nv < 8; nv++)
                attn_out[row * 2048 + h * 128 + nv * 16 + l16] = (bf16)(o[nv][r] * inv);
        }
    }
}

// ---------------------------------------------------------------------------
extern "C" void kernel_launch(void* const* d_in, const int* in_sizes, int n_in,
                              void* d_out, int out_size, void* d_ws, size_t ws_size,
                              hipStream_t stream)
{
    const float* x    = (const float*)d_in[0];
    const float* Wqa  = (const float*)d_in[1];
    const float* Wqb  = (const float*)d_in[2];
    const float* Wkva = (const float*)d_in[3];
    const float* Wkvb = (const float*)d_in[4];
    const float* Wout = (const float*)d_in[5];
    float* out = (float*)d_out;

    char* ws = (char*)d_ws;
    size_t off = 0;
    auto alloc = [&](size_t elems) { char* p = ws + off; off += elems * sizeof(bf16); return (bf16*)p; };
    bf16* xb    = alloc((size_t)ROWS * 2048);   // reused as `attn` later
    bf16* WqaT  = alloc((size_t)512 * 2048);
    bf16* WqbT  = alloc((size_t)3072 * 512);
    bf16* WkvaT = alloc((size_t)640 * 2048);    // rows padded 576->640 for staging
    bf16* WkvbT = alloc((size_t)4096 * 512);
    bf16* WoutT = alloc((size_t)2048 * 2048);
    bf16* t1    = alloc((size_t)ROWS * 512);
    bf16* q     = alloc((size_t)ROWS * 3072);   // reused as vT later (needs 8.4M <= 12.6M)
    bf16* ckv   = alloc((size_t)ROWS * 576);
    bf16* kv    = alloc((size_t)ROWS * 4096);
    bf16* qf    = alloc((size_t)32 * SEQ * QHEAD);
    bf16* kf    = alloc((size_t)32 * SEQ * QHEAD);
    bf16* attn  = xb;                           // alias: xb dead after GEMM1/3
    bf16* vT    = q;                            // alias: q dead after prep_q
    if (off > ws_size) return;                  // distinguishable failure (absmax = max|ref|)

    dim3 blk(256);

    convert_f32_bf16<<<dim3(8192), blk, 0, stream>>>(x, xb, (size_t)ROWS * 2048);

    transpose_f32_bf16<<<dim3(16, 64), blk, 0, stream>>>(Wqa, WqaT, 2048, 512);
    transpose_f32_bf16<<<dim3(96, 16), blk, 0, stream>>>(Wqb, WqbT, 512, 3072);
    transpose_f32_bf16<<<dim3(18, 64), blk, 0, stream>>>(Wkva, WkvaT, 2048, 576);
    transpose_f32_bf16<<<dim3(128, 16), blk, 0, stream>>>(Wkvb, WkvbT, 512, 4096);
    transpose_f32_bf16<<<dim3(64, 64), blk, 0, stream>>>(Wout, WoutT, 2048, 2048);

    // GEMM1: t1 = x @ Wqa          [4096,512]  K=2048
    gemm_bf16<bf16><<<dim3(32, 4), blk, 0, stream>>>(xb, 2048, WqaT, 2048, t1, 512, ROWS, 512, 2048);
    // GEMM3: ckv = x @ Wkva        [4096,576]  K=2048
    gemm_bf16<bf16><<<dim3(32, 5), blk, 0, stream>>>(xb, 2048, WkvaT, 2048, ckv, 576, ROWS, 576, 2048);
    // GEMM2: q = t1 @ Wqb          [4096,3072] K=512
    gemm_bf16<bf16><<<dim3(32, 24), blk, 0, stream>>>(t1, 512, WqbT, 512, q, 3072, ROWS, 3072, 512);
    // GEMM4: kv = ckv[:,:512] @ Wkvb  [4096,4096] K=512
    gemm_bf16<bf16><<<dim3(32, 32), blk, 0, stream>>>(ckv, 576, WkvbT, 512, kv, 4096, ROWS, 4096, 512);

    prep_q<<<dim3(ROWS * 384 / 256), blk, 0, stream>>>(q, qf);      // before vT overwrites q!
    prep_kv<<<dim3(ROWS), blk, 0, stream>>>(ckv, kv, kf);
    vt_kernel<<<dim3(64, 4, 32), blk, 0, stream>>>(kv, vT);

    attn_fa<<<dim3(512), blk, 0, stream>>>(qf, kf, vT, attn);

    // GEMM5: out = attn @ Wout     [4096,2048] K=2048  (fp32 output)
    gemm_bf16<float><<<dim3(32, 16), blk, 0, stream>>>(attn, 2048, WoutT, 2048, out, 2048, ROWS, 2048, 2048);
}

// Round 4
// 452.439 us; speedup vs baseline: 1.9246x; 1.1024x over previous
//
#include <hip/hip_runtime.h>
#include <math.h>

typedef __bf16 bf16;
typedef __bf16 bf16x8 __attribute__((ext_vector_type(8)));
typedef float f32x4 __attribute__((ext_vector_type(4)));

#define HEADS 16
#define QHEAD 192
#define NB 2
#define SEQ 2048
#define ROWS (NB * SEQ)
#define QSCALE 0.07216878364870322f   /* 1/sqrt(192), folded into q */

// ---------------------------------------------------------------------------
// fp32 -> bf16 elementwise convert (for x)
// ---------------------------------------------------------------------------
__global__ __launch_bounds__(256) void convert_f32_bf16(
    const float* __restrict__ in, bf16* __restrict__ out, size_t n)
{
    size_t i = ((size_t)blockIdx.x * 256 + threadIdx.x) * 4;
    if (i + 3 < n) {
        float4 v = *(const float4*)(in + i);
        out[i]     = (bf16)v.x;
        out[i + 1] = (bf16)v.y;
        out[i + 2] = (bf16)v.z;
        out[i + 3] = (bf16)v.w;
    } else {
        for (size_t j = i; j < n; j++) out[j] = (bf16)in[j];
    }
}

// ---------------------------------------------------------------------------
// Transpose + convert: out_bf16[C,R] = in_f32[R,C]
// ---------------------------------------------------------------------------
__global__ __launch_bounds__(256) void transpose_f32_bf16(
    const float* __restrict__ in, bf16* __restrict__ out, int R, int Ccols)
{
    __shared__ float tile[32][33];
    int bx = blockIdx.x * 32, by = blockIdx.y * 32;
    int tx = threadIdx.x & 31, ty = threadIdx.x >> 5;   // 32 x 8
    for (int i = 0; i < 32; i += 8) {
        int r = by + ty + i, c = bx + tx;
        tile[ty + i][tx] = (r < R && c < Ccols) ? in[(size_t)r * Ccols + c] : 0.f;
    }
    __syncthreads();
    for (int i = 0; i < 32; i += 8) {
        int c = bx + ty + i, r = by + tx;
        if (c < Ccols && r < R) out[(size_t)c * R + r] = (bf16)tile[tx][ty + i];
    }
}

// ===========================================================================
// GEMM core body (m97 recipe) as a macro so specialized-epilogue kernels share
// it: 128x128 tile, BK=32, packed LDS, global_load_lds width-16 staging.
// Defines: acc[4][4], tid/wave/lane/quad/l16, bm/bn, wm/wn.
// ===========================================================================
#define GEMM_BODY(Aptr, LDA, Bptr, LDB, KK)                                     \
    __shared__ bf16 As[128 * 32];                                               \
    __shared__ bf16 Bs[128 * 32];                                               \
    const int tid  = threadIdx.x;                                               \
    const int wave = tid >> 6, lane = tid & 63;                                 \
    const int quad = lane >> 4, l16 = lane & 15;                                \
    const int bm = blockIdx.x * 128, bn = blockIdx.y * 128;                     \
    const int wm = (wave >> 1) * 64, wn = (wave & 1) * 64;                      \
    const int srow = lane >> 2, scol = (lane & 3) * 8;                          \
    f32x4 acc[4][4];                                                            \
    for (int i = 0; i < 4; i++)                                                 \
        for (int j = 0; j < 4; j++)                                             \
            acc[i][j] = (f32x4){0.f, 0.f, 0.f, 0.f};                            \
    for (int k0 = 0; k0 < (KK); k0 += 32) {                                     \
        _Pragma("unroll")                                                       \
        for (int s2 = 0; s2 < 2; s2++) {                                        \
            const int seg = wave * 2 + s2;                                      \
            const bf16* ga = (Aptr) + (size_t)(bm + seg * 16 + srow) * (LDA) + k0 + scol; \
            const bf16* gb = (Bptr) + (size_t)(bn + seg * 16 + srow) * (LDB) + k0 + scol; \
            __builtin_amdgcn_global_load_lds(                                   \
                (const __attribute__((address_space(1))) void*)ga,              \
                (__attribute__((address_space(3))) void*)&As[seg * 512], 16, 0, 0); \
            __builtin_amdgcn_global_load_lds(                                   \
                (const __attribute__((address_space(1))) void*)gb,              \
                (__attribute__((address_space(3))) void*)&Bs[seg * 512], 16, 0, 0); \
        }                                                                       \
        __syncthreads();                                                        \
        bf16x8 af[4], bfv[4];                                                   \
        for (int mi = 0; mi < 4; mi++)                                          \
            af[mi] = *(const bf16x8*)&As[(wm + mi * 16 + l16) * 32 + quad * 8]; \
        for (int ni = 0; ni < 4; ni++)                                          \
            bfv[ni] = *(const bf16x8*)&Bs[(wn + ni * 16 + l16) * 32 + quad * 8];\
        for (int mi = 0; mi < 4; mi++)                                          \
            for (int ni = 0; ni < 4; ni++)                                      \
                acc[mi][ni] = __builtin_amdgcn_mfma_f32_16x16x32_bf16(          \
                    af[mi], bfv[ni], acc[mi][ni], 0, 0, 0);                     \
        __syncthreads();                                                        \
    }

// ---------------------------------------------------------------------------
// Generic GEMM with plain epilogue (guards on N)
// ---------------------------------------------------------------------------
template <typename OutT>
__global__ __launch_bounds__(256) void gemm_bf16(
    const bf16* __restrict__ A, int lda,
    const bf16* __restrict__ Bt, int ldb,
    OutT* __restrict__ C, int ldc,
    int N, int K)
{
    GEMM_BODY(A, lda, Bt, ldb, K)
    for (int mi = 0; mi < 4; mi++)
        for (int ni = 0; ni < 4; ni++) {
            int col = bn + wn + ni * 16 + l16;
            if (col >= N) continue;
            int row0 = bm + wm + mi * 16 + quad * 4;
            for (int r = 0; r < 4; r++)
                C[(size_t)(row0 + r) * ldc + col] = (OutT)acc[mi][ni][r];
        }
}

// ---------------------------------------------------------------------------
// GEMM2 fused: q = t1 @ Wqb, epilogue applies RoPE (cols with d>=128 within
// each head) + QSCALE and scatters directly into qf[bh,n,192].
// RoPE pairs (2i,2i+1) are adjacent lanes -> shfl_xor(.,1).
// ---------------------------------------------------------------------------
__global__ __launch_bounds__(256) void gemm_qf(
    const bf16* __restrict__ A, int lda,
    const bf16* __restrict__ Bt, int ldb,
    bf16* __restrict__ qf, int K)
{
    GEMM_BODY(A, lda, Bt, ldb, K)
    const bool odd = l16 & 1;
    for (int mi = 0; mi < 4; mi++)
        for (int ni = 0; ni < 4; ni++) {
            int col0 = bn + wn + ni * 16;      // multiple of 16; 192%16==0 ->
            int h  = col0 / 192;               // head & rope-ness uniform per tile
            int d0 = col0 - h * 192;
            int d  = d0 + l16;
            bool roped = d0 >= 128;
            float theta = 0.f;
            if (roped) theta = powf(10000.f, -(float)((d - 128) >> 1) / 32.f);
            for (int r = 0; r < 4; r++) {
                int row = bm + wm + mi * 16 + quad * 4 + r;
                int b = row >> 11, n = row & 2047;
                float v = acc[mi][ni][r], res;
                if (roped) {
                    float p = __shfl_xor(v, 1);
                    float sn, cs;
                    sincosf((float)n * theta, &sn, &cs);
                    float x1 = odd ? p : v, x2 = odd ? v : p;
                    res = odd ? (x1 * sn + x2 * cs) : (x1 * cs - x2 * sn);
                } else res = v;
                qf[(((size_t)(b * HEADS + h)) * SEQ + n) * QHEAD + d] =
                    (bf16)(res * QSCALE);
            }
        }
}

// ---------------------------------------------------------------------------
// GEMM4 fused: kv = ckv @ Wkvb; epilogue routes k_nope (d<128) into
// kf[bh,n,192] and v (d>=128) into compact kvv[row, h*128+dv].
// ---------------------------------------------------------------------------
__global__ __launch_bounds__(256) void gemm_kv(
    const bf16* __restrict__ A, int lda,
    const bf16* __restrict__ Bt, int ldb,
    bf16* __restrict__ kf, bf16* __restrict__ kvv, int K)
{
    GEMM_BODY(A, lda, Bt, ldb, K)
    for (int mi = 0; mi < 4; mi++)
        for (int ni = 0; ni < 4; ni++) {
            int col0 = bn + wn + ni * 16;
            int h  = col0 >> 8;
            int d0 = col0 & 255;
            int d  = d0 + l16;
            for (int r = 0; r < 4; r++) {
                int row = bm + wm + mi * 16 + quad * 4 + r;
                int b = row >> 11, n = row & 2047;
                bf16 v = (bf16)acc[mi][ni][r];
                if (d0 < 128)
                    kf[(((size_t)(b * HEADS + h)) * SEQ + n) * QHEAD + d] = v;
                else
                    kvv[(size_t)row * 2048 + h * 128 + (d - 128)] = v;
            }
        }
}

// ---------------------------------------------------------------------------
// rope_kpe: fill kf[bh,n,128..191] from tc cols 1024..1087 (k_pe), roped,
// broadcast over 16 heads.
// ---------------------------------------------------------------------------
__global__ __launch_bounds__(64) void rope_kpe(
    const bf16* __restrict__ tc, bf16* __restrict__ kf)
{
    int row = blockIdx.x, j = threadIdx.x;    // j = 0..63
    int b = row >> 11, n = row & 2047;
    int i = j >> 1;
    float x1 = (float)tc[(size_t)row * 1152 + 1024 + 2 * i];
    float x2 = (float)tc[(size_t)row * 1152 + 1024 + 2 * i + 1];
    float theta = powf(10000.f, -(float)i / 32.f);
    float sn, cs;
    sincosf((float)n * theta, &sn, &cs);
    bf16 rv = (bf16)((j & 1) ? (x1 * sn + x2 * cs) : (x1 * cs - x2 * sn));
    for (int h = 0; h < HEADS; h++)
        kf[(((size_t)(b * HEADS + h)) * SEQ + n) * QHEAD + 128 + j] = rv;
}

// ---------------------------------------------------------------------------
// vT[bh,dv,n] = kvv[b*SEQ+n, h*128+dv]
// ---------------------------------------------------------------------------
__global__ __launch_bounds__(256) void vt_kernel(
    const bf16* __restrict__ kvv, bf16* __restrict__ vT)
{
    __shared__ bf16 tile[32][33];
    int nt0 = blockIdx.x * 32;
    int dv0 = blockIdx.y * 32;
    int bh  = blockIdx.z;
    int b = bh >> 4, h = bh & 15;
    int tx = threadIdx.x & 31, ty = threadIdx.x >> 5;
    for (int i = 0; i < 32; i += 8) {
        int n = nt0 + ty + i;
        tile[ty + i][tx] = kvv[((size_t)(b * SEQ + n)) * 2048 + h * 128 + dv0 + tx];
    }
    __syncthreads();
    for (int i = 0; i < 32; i += 8) {
        int dv = dv0 + ty + i;
        vT[((size_t)bh * 128 + dv) * SEQ + nt0 + tx] = tile[tx][ty + i];
    }
}

// ---------------------------------------------------------------------------
// Flash attention, causal, XCD-swizzled: all 16 q-tile blocks of a bh land on
// one XCD (assuming round-robin bid%8 dispatch) so the K/V stream stays in
// that XCD's 4 MiB L2. Each block does passes qt=pk and qt=31-pk (33 iters).
// ---------------------------------------------------------------------------
__global__ __launch_bounds__(256) void attn_fa(
    const bf16* __restrict__ qf, const bf16* __restrict__ kf,
    const bf16* __restrict__ vT, bf16* __restrict__ attn_out)
{
    __shared__ bf16 Ks[64][200];
    __shared__ bf16 Vt[128][72];
    __shared__ bf16 Ps[4][16][72];

    const int bid = blockIdx.x;
    const int xcd = bid & 7, j = bid >> 3;
    const int bh = xcd + 8 * (j & 3);   // 4 bh per XCD
    const int pk = j >> 2;              // 0..15
    const int b = bh >> 4, h = bh & 15;
    const int tid  = threadIdx.x;
    const int wave = tid >> 6, lane = tid & 63;
    const int quad = lane >> 4, l16 = lane & 15;

    for (int pass = 0; pass < 2; pass++) {
        const int qt = pass ? (31 - pk) : pk;

        bf16x8 aq[6];
        {
            const bf16* qbase = qf + ((size_t)bh * SEQ + qt * 64 + wave * 16 + l16) * QHEAD;
            for (int ks = 0; ks < 6; ks++)
                aq[ks] = *(const bf16x8*)(qbase + ks * 32 + quad * 8);
        }
        f32x4 o[8];
        for (int i = 0; i < 8; i++) o[i] = (f32x4){0.f, 0.f, 0.f, 0.f};
        float m_i[4] = {-1e30f, -1e30f, -1e30f, -1e30f};
        float l_i[4] = {0.f, 0.f, 0.f, 0.f};

        for (int kt = 0; kt <= qt; kt++) {
#pragma unroll
            for (int i = 0; i < 6; i++) {
                int c = tid + i * 256;
                int r = c / 24, col = (c - r * 24) * 8;
                *(uint4*)&Ks[r][col] =
                    *(const uint4*)(kf + ((size_t)bh * SEQ + kt * 64 + r) * QHEAD + col);
            }
#pragma unroll
            for (int i = 0; i < 4; i++) {
                int c = tid + i * 256;
                int dv = c >> 3, g = c & 7;
                *(uint4*)&Vt[dv][g * 8] =
                    *(const uint4*)(vT + ((size_t)bh * 128 + dv) * SEQ + kt * 64 + g * 8);
            }
            __syncthreads();

            f32x4 sacc[4];
            for (int nt = 0; nt < 4; nt++) sacc[nt] = (f32x4){0.f, 0.f, 0.f, 0.f};
            for (int ks = 0; ks < 6; ks++)
                for (int nt = 0; nt < 4; nt++) {
                    bf16x8 bk = *(const bf16x8*)&Ks[nt * 16 + l16][ks * 32 + quad * 8];
                    sacc[nt] = __builtin_amdgcn_mfma_f32_16x16x32_bf16(aq[ks], bk, sacc[nt], 0, 0, 0);
                }

            const bool diag = (kt == qt);
            float ptile[4][4];
            for (int r = 0; r < 4; r++) {
                float mx = m_i[r];
                if (diag) {
                    int qrow = wave * 16 + quad * 4 + r;
                    for (int nt = 0; nt < 4; nt++) {
                        int kp = nt * 16 + l16;
                        float s = (kp > qrow) ? -1e30f : sacc[nt][r];
                        ptile[nt][r] = s;
                        mx = fmaxf(mx, s);
                    }
                } else {
                    for (int nt = 0; nt < 4; nt++) {
                        float s = sacc[nt][r];
                        ptile[nt][r] = s;
                        mx = fmaxf(mx, s);
                    }
                }
                mx = fmaxf(mx, __shfl_xor(mx, 8));
                mx = fmaxf(mx, __shfl_xor(mx, 4));
                mx = fmaxf(mx, __shfl_xor(mx, 2));
                mx = fmaxf(mx, __shfl_xor(mx, 1));
                float alpha = __expf(m_i[r] - mx);
                float rs = 0.f;
                for (int nt = 0; nt < 4; nt++) {
                    float p = __expf(ptile[nt][r] - mx);
                    ptile[nt][r] = p;
                    rs += p;
                }
                rs += __shfl_xor(rs, 8);
                rs += __shfl_xor(rs, 4);
                rs += __shfl_xor(rs, 2);
                rs += __shfl_xor(rs, 1);
                l_i[r] = l_i[r] * alpha + rs;
                m_i[r] = mx;
                for (int nv = 0; nv < 8; nv++) o[nv][r] *= alpha;
            }

            // P: C-layout -> A-layout via wave-private LDS (no block barrier)
            for (int nt = 0; nt < 4; nt++)
                for (int r = 0; r < 4; r++)
                    Ps[wave][quad * 4 + r][nt * 16 + l16] = (bf16)ptile[nt][r];
            __builtin_amdgcn_sched_barrier(0);

            for (int ks2 = 0; ks2 < 2; ks2++) {
                bf16x8 ap = *(const bf16x8*)&Ps[wave][l16][ks2 * 32 + quad * 8];
                for (int nv = 0; nv < 8; nv++) {
                    bf16x8 bv = *(const bf16x8*)&Vt[nv * 16 + l16][ks2 * 32 + quad * 8];
                    o[nv] = __builtin_amdgcn_mfma_f32_16x16x32_bf16(ap, bv, o[nv], 0, 0, 0);
                }
            }
            __syncthreads();
        }

        for (int r = 0; r < 4; r++) {
            float inv = 1.f / l_i[r];
            size_t row = (size_t)b * SEQ + qt * 64 + wave * 16 + quad * 4 + r;
            for (int nv = 0; nv < 8; nv++)
                attn_out[row * 2048 + h * 128 + nv * 16 + l16] = (bf16)(o[nv][r] * inv);
        }
    }
}

// ---------------------------------------------------------------------------
extern "C" void kernel_launch(void* const* d_in, const int* in_sizes, int n_in,
                              void* d_out, int out_size, void* d_ws, size_t ws_size,
                              hipStream_t stream)
{
    const float* x    = (const float*)d_in[0];
    const float* Wqa  = (const float*)d_in[1];
    const float* Wqb  = (const float*)d_in[2];
    const float* Wkva = (const float*)d_in[3];
    const float* Wkvb = (const float*)d_in[4];
    const float* Wout = (const float*)d_in[5];
    float* out = (float*)d_out;

    char* ws = (char*)d_ws;
    size_t off = 0;
    auto alloc = [&](size_t elems) { char* p = ws + off; off += elems * sizeof(bf16); return (bf16*)p; };
    bf16* xb    = alloc((size_t)ROWS * 2048);   // reused as `attn` later
    bf16* WfT   = alloc((size_t)1152 * 2048);   // [WqaT(512) ; WkvaT(576) ; pad]
    bf16* WqbT  = alloc((size_t)3072 * 512);
    bf16* WkvbT = alloc((size_t)4096 * 512);
    bf16* WoutT = alloc((size_t)2048 * 2048);
    bf16* tc    = alloc((size_t)ROWS * 1152);   // [t1(512) | ckv(512) | k_pe(64) | pad]
    bf16* kvv   = alloc((size_t)ROWS * 2048);   // v only, [row][h*128+dv]
    bf16* vT    = alloc((size_t)32 * 128 * SEQ);
    bf16* qf    = alloc((size_t)32 * SEQ * QHEAD);
    bf16* kf    = alloc((size_t)32 * SEQ * QHEAD);
    bf16* attn  = xb;                           // alias: xb dead after gemm13
    if (off > ws_size) return;                  // distinguishable failure

    dim3 blk(256);

    convert_f32_bf16<<<dim3(8192), blk, 0, stream>>>(x, xb, (size_t)ROWS * 2048);

    transpose_f32_bf16<<<dim3(16, 64), blk, 0, stream>>>(Wqa, WfT, 2048, 512);
    transpose_f32_bf16<<<dim3(18, 64), blk, 0, stream>>>(Wkva, WfT + (size_t)512 * 2048, 2048, 576);
    transpose_f32_bf16<<<dim3(96, 16), blk, 0, stream>>>(Wqb, WqbT, 512, 3072);
    transpose_f32_bf16<<<dim3(128, 16), blk, 0, stream>>>(Wkvb, WkvbT, 512, 4096);
    transpose_f32_bf16<<<dim3(64, 64), blk, 0, stream>>>(Wout, WoutT, 2048, 2048);

    // GEMM1+3 fused: tc[:,0:1088] = x @ [Wqa | Wkva]   K=2048
    gemm_bf16<bf16><<<dim3(32, 9), blk, 0, stream>>>(xb, 2048, WfT, 2048, tc, 1152, 1088, 2048);
    // GEMM2 fused epilogue -> qf (RoPE + scale):  t1 @ Wqb, K=512
    gemm_qf<<<dim3(32, 24), blk, 0, stream>>>(tc, 1152, WqbT, 512, qf, 512);
    // GEMM4 fused epilogue -> kf (k_nope) + kvv (v):  ckv @ Wkvb, K=512
    gemm_kv<<<dim3(32, 32), blk, 0, stream>>>(tc + 512, 1152, WkvbT, 512, kf, kvv, 512);
    // k_pe RoPE broadcast into kf
    rope_kpe<<<dim3(ROWS), dim3(64), 0, stream>>>(tc, kf);
    // V transpose for attention B-fragments
    vt_kernel<<<dim3(64, 4, 32), blk, 0, stream>>>(kvv, vT);

    attn_fa<<<dim3(512), blk, 0, stream>>>(qf, kf, vT, attn);

    // GEMM5: out = attn @ Wout   [4096,2048] K=2048  (fp32 output)
    gemm_bf16<float><<<dim3(32, 16), blk, 0, stream>>>(attn, 2048, WoutT, 2048, out, 2048, 2048, 2048);
}